// Round 11
// baseline (120.969 us; speedup 1.0000x reference)
//
#include <hip/hip_runtime.h>

typedef __bf16 bf16;
typedef __bf16 bf16x4 __attribute__((ext_vector_type(4)));
typedef __bf16 bf16x8 __attribute__((ext_vector_type(8)));
typedef float  f32x4  __attribute__((ext_vector_type(4)));
typedef float  f32x16 __attribute__((ext_vector_type(16)));

#define CIN    256
#define KK     9
#define KDIM   2304
#define KSTEPS 144           // KDIM / 16 (32x32x16 k-steps)
#define PXW    32            // pixels per WG

// force a wave-uniform value into an SGPR
__device__ __forceinline__ float sread(float f) {
    return __builtin_bit_cast(float,
        __builtin_amdgcn_readfirstlane(__builtin_bit_cast(int, f)));
}
__device__ __forceinline__ int sreadi(int v) {
    return __builtin_amdgcn_readfirstlane(v);
}

// ---------------------------------------------------------------------------
// Fused prep: blocks [0,1024) transpose x -> channels-last bf16 xt;
//             blocks [1024,3328) pack weight for 32x32x16 A-fragments:
//   wq[ ((mt*144 + KT)*64 + L)*8 + j ] = W[o = mt*32 + (L&31)]
//                                         [k = KT*16 + (L>>5)*8 + j]
//   (A-frag layout for mfma_32x32x16: m = lane&31, k = (lane>>5)*8 + j.)
//   k -> (tap = k>>8, ch = k&255), W src = w[o][ch][tap].
// ---------------------------------------------------------------------------
__global__ __launch_bounds__(256) void prep_k(const float* __restrict__ x,
                                              const float* __restrict__ w,
                                              bf16* __restrict__ xt,
                                              bf16* __restrict__ wq) {
    int bid = blockIdx.x;
    int tid = threadIdx.x;
    if (bid < 1024) {
        __shared__ bf16 tile[64][72];        // px-major; rows 144 B
        int pt = bid & 63, ct = (bid >> 6) & 3, b = bid >> 8;
        int lane = tid & 63, row = tid >> 6;
        const float* src = x + ((size_t)(b * 256 + ct * 64)) * 4096 + pt * 64;
        #pragma unroll
        for (int cc = row; cc < 64; cc += 4)
            tile[lane][cc] = (bf16)src[(size_t)cc * 4096 + lane];
        __syncthreads();
        bf16* dst = xt + ((size_t)(b * 4096 + pt * 64)) * 256 + ct * 64;
        int p = tid >> 3, j = tid & 7;
        #pragma unroll
        for (int pp = p; pp < 64; pp += 32)
            *reinterpret_cast<bf16x8*>(dst + (size_t)pp * 256 + j * 8) =
                *reinterpret_cast<const bf16x8*>(&tile[pp][j * 8]);
    } else {
        int idx  = (bid - 1024) * 256 + tid;   // < 589824
        int j    = idx & 7;
        int L    = (idx >> 3) & 63;
        int rest = idx >> 9;                   // mt*144 + KT
        int KT   = rest % KSTEPS;
        int mt   = rest / KSTEPS;              // 0..7
        int o    = mt * 32 + (L & 31);
        int kg   = KT * 16 + ((L >> 5) << 3) + j;
        int tap  = kg >> 8;
        int ch   = kg & 255;
        wq[idx] = (bf16)w[(size_t)o * KDIM + ch * 9 + tap];
    }
}

// ---------------------------------------------------------------------------
// Fused sampling -> LDS -> 32x32x16 MFMA GEMM.
// WG = 1024 thr (16 waves), PXW=32, grid 512 -> 2 WG/CU = 32 waves/CU.
// Wave (wavei): mtile mt = wavei&7 (M32), khalf kh = wavei>>3 (8 of the 16
// k-steps per tap). K-split partials reduced through LDS in the epilogue.
// vs r10 (16x16x32): one ds_read_b128 B-frag now feeds 2x the FLOPs ->
// LDS reads, MFMA issue, A-loads, GEMM addressing all halve (r10 evidence:
// LDS ~60% busy was the top pipe; occupancy doubling was nearly neutral).
// S: 5-bit XOR granule swizzle (granule g of px p stored at g^p): writes are
// a permutation; B-reads (stride 512 B) spread evenly over all 32 banks.
// XCD band swizzle kept (r5: FETCH 33.5 -> 10.3 MB); tap rotation desync;
// one barrier per tap with double-buffered S (r10 scheme).
// ---------------------------------------------------------------------------
__global__ __launch_bounds__(1024, 8) void deform_gemm_k(
    const bf16*  __restrict__ xt,
    const float* __restrict__ off,
    const bf16*  __restrict__ wq,
    const float* __restrict__ bias,
    float*       __restrict__ out) {

    __shared__ bf16 S[2][PXW * 256];   // 2 x 16 KB, swizzled granules

    int tid   = threadIdx.x;
    int wavei = sreadi(tid >> 6);   // 0..15
    int lane  = tid & 63;
    int px32  = lane & 31;          // B/C col, pixel within tile
    int khl   = lane >> 5;          // k-group within fragment
    int mt    = wavei & 7;          // mtile (M32)
    int kh    = wavei >> 3;         // k-half of each tap

    int bid   = blockIdx.x;                      // 0..511
    int pb    = ((bid & 7) << 6) | (bid >> 3);   // XCD-band pixel-block
    int pix0  = pb * PXW;
    int b     = pix0 >> 12;                      // WG-uniform batch
    int pimgb = pix0 & 4095;
    int obase = b * 73728;                       // scalar base into off[]
    unsigned base = (unsigned)b * 1048576u + (unsigned)(lane * 4); // into xt[]
    int rot   = ((bid >> 3) & 1) * 4;            // co-resident WG desync

    f32x16 acc;
    #pragma unroll
    for (int r = 0; r < 16; ++r) acc[r] = 0.f;

    for (int t = 0; t < KK; ++t) {
        int tap = t + rot; if (tap >= KK) tap -= KK;
        int ty = tap / 3 - 1;
        int tx = tap % 3 - 1;
        bf16* Sw = &S[t & 1][0];

        // ---- sampling: wave fills rows n = wavei*2, wavei*2+1 ----
        #pragma unroll
        for (int i = 0; i < 2; ++i) {
            int n    = wavei * 2 + i;
            int pimg = pimgb + n;                          // scalar
            float oy = off[obase + pimg + (2 * tap) * 4096];      // s_load
            float ox = off[obase + pimg + (2 * tap + 1) * 4096];  // s_load
            float py = (float)((pimg >> 6) + ty) + oy;
            float px = (float)((pimg & 63) + tx) + ox;
            float fy = floorf(py), fx = floorf(px);
            int   y0 = (int)fy,    x0 = (int)fx;
            float wy1 = py - fy, wx1 = px - fx;
            float wy0 = 1.f - wy1, wx0 = 1.f - wx1;
            wy0 = ((unsigned)y0       < 64u) ? wy0 : 0.f;
            wy1 = ((unsigned)(y0 + 1) < 64u) ? wy1 : 0.f;
            wx0 = ((unsigned)x0       < 64u) ? wx0 : 0.f;
            wx1 = ((unsigned)(x0 + 1) < 64u) ? wx1 : 0.f;
            int yc0 = min(max(y0, 0), 63), yc1 = min(max(y0 + 1, 0), 63);
            int xc0 = min(max(x0, 0), 63), xc1 = min(max(x0 + 1, 0), 63);
            int u0 = sreadi((yc0 * 64 + xc0) * 256);
            int u1 = sreadi((yc0 * 64 + xc1) * 256);
            int u2 = sreadi((yc1 * 64 + xc0) * 256);
            int u3 = sreadi((yc1 * 64 + xc1) * 256);
            float w0 = sread(wy0 * wx0), w1 = sread(wy0 * wx1);
            float w2 = sread(wy1 * wx0), w3 = sread(wy1 * wx1);
            bf16x4 v0 = *reinterpret_cast<const bf16x4*>(xt + base + (unsigned)u0);
            bf16x4 v1 = *reinterpret_cast<const bf16x4*>(xt + base + (unsigned)u1);
            bf16x4 v2 = *reinterpret_cast<const bf16x4*>(xt + base + (unsigned)u2);
            bf16x4 v3 = *reinterpret_cast<const bf16x4*>(xt + base + (unsigned)u3);
            float a0 = w0 * (float)v0[0] + w1 * (float)v1[0]
                     + w2 * (float)v2[0] + w3 * (float)v3[0];
            float a1 = w0 * (float)v0[1] + w1 * (float)v1[1]
                     + w2 * (float)v2[1] + w3 * (float)v3[1];
            float a2 = w0 * (float)v0[2] + w1 * (float)v1[2]
                     + w2 * (float)v2[2] + w3 * (float)v3[2];
            float a3 = w0 * (float)v0[3] + w1 * (float)v1[3]
                     + w2 * (float)v2[3] + w3 * (float)v3[3];
            bf16x4 sv;
            sv[0] = (bf16)a0; sv[1] = (bf16)a1;
            sv[2] = (bf16)a2; sv[3] = (bf16)a3;
            int gw = lane >> 1;                  // 8-ch granule 0..31
            int gs = gw ^ n;                     // 5-bit XOR swizzle
            *reinterpret_cast<bf16x4*>(Sw + n * 256 + gs * 8 + (lane & 1) * 4) = sv;
        }
        __syncthreads();

        // ---- GEMM: wave = mtile mt x N32, k-steps kh*8 .. kh*8+7 ----
        const bf16* Sr = Sw;
        #pragma unroll
        for (int kk = 0; kk < 8; ++kk) {
            int KT = tap * 16 + kh * 8 + kk;     // global k-step
            bf16x8 a = *reinterpret_cast<const bf16x8*>(
                wq + ((size_t)((mt * KSTEPS + KT) * 64 + lane)) * 8);
            int g  = (kh * 8 + kk) * 2 + khl;    // within-tap 8-ch granule
            int gs = g ^ px32;                   // 5-bit XOR swizzle
            bf16x8 bb = *reinterpret_cast<const bf16x8*>(
                Sr + px32 * 256 + gs * 8);
            acc = __builtin_amdgcn_mfma_f32_32x32x16_bf16(a, bb, acc, 0, 0, 0);
        }
        // no trailing barrier: next tap writes the OTHER buffer; re-write of
        // this buffer (t+2) is ordered behind barrier t+1.
    }
    __syncthreads();   // all B-reads done before S is reused for reduction

    // ---- K-split reduction through LDS: kh=1 partials -> kh=0 waves ----
    float* Sf = (float*)&S[0][0];               // 32 KB = 8 waves x 4 KB
    if (kh == 1) {
        float* p = Sf + (size_t)(mt * 64 + lane) * 16;
        #pragma unroll
        for (int q = 0; q < 4; ++q)
            *reinterpret_cast<f32x4*>(p + q * 4) =
                (f32x4){acc[q*4+0], acc[q*4+1], acc[q*4+2], acc[q*4+3]};
    }
    __syncthreads();

    if (kh == 0) {
        const float* p = Sf + (size_t)(mt * 64 + lane) * 16;
        #pragma unroll
        for (int r = 0; r < 16; ++r) acc[r] += p[r];

        // C/D layout (32x32): col = lane&31, row = (reg&3)+8*(reg>>2)+4*(lane>>5)
        int pimg = pimgb + px32;
        #pragma unroll
        for (int r = 0; r < 16; ++r) {
            int row = (r & 3) + 8 * (r >> 2) + 4 * khl;
            int o   = mt * 32 + row;
            out[((size_t)(b * 256 + o)) * 4096 + pimg] = acc[r] + bias[o];
        }
    }
}

// ---------------------------------------------------------------------------
extern "C" void kernel_launch(void* const* d_in, const int* in_sizes, int n_in,
                              void* d_out, int out_size, void* d_ws, size_t ws_size,
                              hipStream_t stream) {
    const float* x    = (const float*)d_in[0];   // [4,256,64,64]
    const float* off  = (const float*)d_in[1];   // [4,18,64,64]
    const float* w    = (const float*)d_in[2];   // [256,256,3,3]
    const float* bias = (const float*)d_in[3];   // [256]
    float* out = (float*)d_out;                  // [4,256,64,64]

    bf16* wq = (bf16*)d_ws;                               // 1,179,648 B
    bf16* xt = (bf16*)((char*)d_ws + (size_t)589824 * 2); // 8,388,608 B

    prep_k<<<3328, 256, 0, stream>>>(x, w, xt, wq);
    deform_gemm_k<<<512, 1024, 0, stream>>>(xt, off, wq, bias, out);
}